// Round 2
// baseline (1344.046 us; speedup 1.0000x reference)
//
#include <hip/hip_runtime.h>
#include <cstdint>
#include <cstddef>

#define Bz 8
#define Nn 2048
#define Ff 256
#define OUTD 256
#define KD 32

// ---------------- k_xk: XK[b,n,k] = sum_f X[b,n,f]*K[f,k] + Kb[k] ----------------
__global__ __launch_bounds__(256) void k_xk(const float* __restrict__ X,
                                            const float* __restrict__ K,
                                            const float* __restrict__ Kb,
                                            float* __restrict__ XK) {
  int k = threadIdx.x & 31;
  int rl = threadIdx.x >> 5;                 // 0..7
  int row = blockIdx.x * 8 + rl;             // global row in [0, B*N)
  const float* xr = X + (size_t)row * Ff;
  float acc = Kb[k];
#pragma unroll 8
  for (int f = 0; f < Ff; ++f) acc += xr[f] * K[f * KD + k];
  XK[(size_t)row * KD + k] = acc;
}

// ---------------- k_deg: isq[b,i] = rsqrt(1 + sum_j A_ij * sigmoid(XK_i . XK_j)) ----------------
__global__ __launch_bounds__(256) void k_deg(const float* __restrict__ A,
                                             const float* __restrict__ XK,
                                             float* __restrict__ isq) {
  int b = blockIdx.x >> 7;                   // 128 tiles of 16 rows per batch
  int i0 = (blockIdx.x & 127) * 16;
  const float* Ab = A + (size_t)b * Nn * Nn;
  const float* XKb = XK + (size_t)b * Nn * KD;
  __shared__ float XKi[16][36];
  int tid = threadIdx.x;
  if (tid < 128) {
    int r = tid >> 3, c = (tid & 7) * 4;
    float4 v = *(const float4*)(XKb + (size_t)(i0 + r) * KD + c);
    XKi[r][c] = v.x; XKi[r][c + 1] = v.y; XKi[r][c + 2] = v.z; XKi[r][c + 3] = v.w;
  }
  __syncthreads();
  float part[16];
#pragma unroll
  for (int r = 0; r < 16; ++r) part[r] = 0.f;
  for (int jj = tid; jj < Nn; jj += 256) {
    float kj[KD];
    const float* kjp = XKb + (size_t)jj * KD;
#pragma unroll
    for (int c = 0; c < KD; c += 4) {
      float4 v = *(const float4*)(kjp + c);
      kj[c] = v.x; kj[c + 1] = v.y; kj[c + 2] = v.z; kj[c + 3] = v.w;
    }
#pragma unroll
    for (int r = 0; r < 16; ++r) {
      float d = 0.f;
#pragma unroll
      for (int c = 0; c < KD; ++c) d += XKi[r][c] * kj[c];
      float s = 1.f / (1.f + __expf(-d));
      part[r] += Ab[(size_t)(i0 + r) * Nn + jj] * s;
    }
  }
#pragma unroll
  for (int r = 0; r < 16; ++r)
    for (int m = 1; m < 64; m <<= 1)
      part[r] += __shfl_xor(part[r], m, 64);
  __shared__ float degS[4][16];
  int wave = tid >> 6, lane = tid & 63;
  if (lane == 0) {
#pragma unroll
    for (int r = 0; r < 16; ++r) degS[wave][r] = part[r];
  }
  __syncthreads();
  if (tid < 16) {
    float deg = 1.f + degS[0][tid] + degS[1][tid] + degS[2][tid] + degS[3][tid];
    isq[(size_t)b * Nn + i0 + tid] = rsqrtf(deg);   // deg >= 1 always
  }
}

// ---------------- k_xw: XWs[row,o] = (sum_f X[row,f]*W[f,o] + Wb[o]) * isq[row] ----------------
__global__ __launch_bounds__(256) void k_xw(const float* __restrict__ X,
                                            const float* __restrict__ W,
                                            const float* __restrict__ Wb,
                                            const float* __restrict__ isq,
                                            float* __restrict__ XWs) {
  __shared__ float Xs[8][Ff];
  int row0 = blockIdx.x * 8;
  int tid = threadIdx.x;
#pragma unroll
  for (int p = 0; p < 2; ++p) {
    int idx = tid + p * 256;                 // float4 index into 8x256 tile
    int r = idx >> 6, c = (idx & 63) * 4;
    *(float4*)&Xs[r][c] = *(const float4*)(X + (size_t)(row0 + r) * Ff + c);
  }
  __syncthreads();
  int o = tid;
  float bias = Wb[o];
  float acc[8];
#pragma unroll
  for (int r = 0; r < 8; ++r) acc[r] = bias;
  for (int f = 0; f < Ff; ++f) {
    float w = W[f * OUTD + o];
#pragma unroll
    for (int r = 0; r < 8; ++r) acc[r] += Xs[r][f] * w;
  }
#pragma unroll
  for (int r = 0; r < 8; ++r)
    XWs[(size_t)(row0 + r) * OUTD + o] = acc[r] * isq[row0 + r];
}

// ---------------- k_main: out = relu(isq_i * (sum_j M_ij * XWs_j + XWs_i)) ----------------
// M_ij = A_ij * sigmoid(XK_i . XK_j).  Tile: 32 i-rows x full 256 o-cols per block.
__global__ __launch_bounds__(256) void k_main(const float* __restrict__ A,
                                              const float* __restrict__ XK,
                                              const float* __restrict__ XWs,
                                              const float* __restrict__ isq,
                                              float* __restrict__ out) {
  int b = blockIdx.x >> 6;                   // 64 i-tiles per batch
  int i0 = (blockIdx.x & 63) * 32;
  const float* Ab = A + (size_t)b * Nn * Nn;
  const float* XKb = XK + (size_t)b * Nn * KD;
  const float* XWb = XWs + (size_t)b * Nn * OUTD;
  __shared__ float XKi[32][33];
  __shared__ float XKj[32][33];
  __shared__ float At[32][36];
  __shared__ float Mt[32][33];
  __shared__ float Bt[32][OUTD];
  int tid = threadIdx.x;
  {
    int r = tid >> 3, c = (tid & 7) * 4;
    float4 v = *(const float4*)(XKb + (size_t)(i0 + r) * KD + c);
    XKi[r][c] = v.x; XKi[r][c + 1] = v.y; XKi[r][c + 2] = v.z; XKi[r][c + 3] = v.w;
  }
  int to = tid & 31, ti = tid >> 5;          // to: 0..31 (o), ti: 0..7 (i)
  float acc[4][8];
#pragma unroll
  for (int r = 0; r < 4; ++r)
#pragma unroll
    for (int q = 0; q < 8; ++q) acc[r][q] = 0.f;

  for (int j0 = 0; j0 < Nn; j0 += 32) {
    __syncthreads();
    {
      int r = tid >> 3, c = (tid & 7) * 4;
      float4 v = *(const float4*)(XKb + (size_t)(j0 + r) * KD + c);
      XKj[r][c] = v.x; XKj[r][c + 1] = v.y; XKj[r][c + 2] = v.z; XKj[r][c + 3] = v.w;
      float4 a = *(const float4*)(Ab + (size_t)(i0 + r) * Nn + j0 + c);
      *(float4*)&At[r][c] = a;
    }
#pragma unroll
    for (int p = 0; p < 8; ++p) {
      int idx = tid + p * 256;
      int r = idx >> 6, c = (idx & 63) * 4;
      *(float4*)&Bt[r][c] = *(const float4*)(XWb + (size_t)(j0 + r) * OUTD + c);
    }
    __syncthreads();
#pragma unroll
    for (int e = 0; e < 4; ++e) {
      int idx = tid + e * 256;
      int mi = idx >> 5, mj = idx & 31;
      float d = 0.f;
#pragma unroll
      for (int c = 0; c < KD; ++c) d += XKi[mi][c] * XKj[mj][c];
      float s = 1.f / (1.f + __expf(-d));
      Mt[mi][mj] = At[mi][mj] * s;
    }
    __syncthreads();
#pragma unroll 8
    for (int j = 0; j < 32; ++j) {
      float av[4];
      av[0] = Mt[ti][j];
      av[1] = Mt[ti + 8][j];
      av[2] = Mt[ti + 16][j];
      av[3] = Mt[ti + 24][j];
      float4 b0 = *(const float4*)&Bt[j][to * 8];
      float4 b1 = *(const float4*)&Bt[j][to * 8 + 4];
#pragma unroll
      for (int r = 0; r < 4; ++r) {
        acc[r][0] += av[r] * b0.x; acc[r][1] += av[r] * b0.y;
        acc[r][2] += av[r] * b0.z; acc[r][3] += av[r] * b0.w;
        acc[r][4] += av[r] * b1.x; acc[r][5] += av[r] * b1.y;
        acc[r][6] += av[r] * b1.z; acc[r][7] += av[r] * b1.w;
      }
    }
  }
#pragma unroll
  for (int r = 0; r < 4; ++r) {
    int i = i0 + ti + r * 8;
    float s = isq[(size_t)b * Nn + i];
    const float* dg = XWb + (size_t)i * OUTD + to * 8;
    float4 d0 = *(const float4*)dg;
    float4 d1 = *(const float4*)(dg + 4);
    float4 v0, v1;
    v0.x = fmaxf(0.f, s * (acc[r][0] + d0.x));
    v0.y = fmaxf(0.f, s * (acc[r][1] + d0.y));
    v0.z = fmaxf(0.f, s * (acc[r][2] + d0.z));
    v0.w = fmaxf(0.f, s * (acc[r][3] + d0.w));
    v1.x = fmaxf(0.f, s * (acc[r][4] + d1.x));
    v1.y = fmaxf(0.f, s * (acc[r][5] + d1.y));
    v1.z = fmaxf(0.f, s * (acc[r][6] + d1.z));
    v1.w = fmaxf(0.f, s * (acc[r][7] + d1.w));
    float* op = out + ((size_t)b * Nn + i) * OUTD + to * 8;
    *(float4*)op = v0;
    *(float4*)(op + 4) = v1;
  }
}

// ---------------- n passthrough as float ----------------
__global__ void k_n(const int* __restrict__ n, float* __restrict__ o) {
  if (threadIdx.x < Bz) o[threadIdx.x] = (float)n[threadIdx.x];
}

extern "C" void kernel_launch(void* const* d_in, const int* in_sizes, int n_in,
                              void* d_out, int out_size, void* d_ws, size_t ws_size,
                              hipStream_t stream) {
  const float* X  = (const float*)d_in[0];
  const float* A  = (const float*)d_in[1];
  const int*   nI = (const int*)d_in[2];
  const float* W  = (const float*)d_in[3];
  const float* Wb = (const float*)d_in[4];
  const float* K  = (const float*)d_in[5];
  const float* Kb = (const float*)d_in[6];

  float* outX = (float*)d_out;                              // [8,2048,256]
  float* outA = outX + (size_t)Bz * Nn * OUTD;              // [8,2048,2048]
  float* outN = outA + (size_t)Bz * Nn * Nn;                // [8]

  float* XKw  = (float*)d_ws;                               // B*N*KD
  float* isq  = XKw + (size_t)Bz * Nn * KD;                 // B*N
  float* XWs  = isq + (size_t)Bz * Nn;                      // B*N*OUTD

  // A passthrough + n passthrough (independent of compute)
  hipMemcpyAsync(outA, A, (size_t)Bz * Nn * Nn * sizeof(float),
                 hipMemcpyDeviceToDevice, stream);
  k_n<<<1, 64, 0, stream>>>(nI, outN);

  k_xk<<<dim3(Bz * Nn / 8), dim3(256), 0, stream>>>(X, K, Kb, XKw);
  k_deg<<<dim3(Bz * (Nn / 16)), dim3(256), 0, stream>>>(A, XKw, isq);
  k_xw<<<dim3(Bz * Nn / 8), dim3(256), 0, stream>>>(X, W, Wb, isq, XWs);
  k_main<<<dim3(Bz * (Nn / 32)), dim3(256), 0, stream>>>(A, XKw, XWs, isq, outX);
}

// Round 4
// 484.690 us; speedup vs baseline: 2.7730x; 2.7730x over previous
//
#include <hip/hip_runtime.h>
#include <cstdint>
#include <cstddef>

#define Bz 8
#define Nn 2048
#define Ff 256
#define OUTD 256
#define KD 32

typedef __attribute__((ext_vector_type(8))) short bf16x8;
typedef __attribute__((ext_vector_type(4))) float f32x4;
typedef unsigned short ushort_t;

__device__ __forceinline__ ushort_t f2bf(float f) {
  union { float f; unsigned int u; } v; v.f = f;
  unsigned int r = v.u + 0x7FFFu + ((v.u >> 16) & 1u);   // round-to-nearest-even
  return (ushort_t)(r >> 16);
}

// ---------------- k_xk: XKbf[b,n,k] = bf16( X@K + Kb ) ----------------
__global__ __launch_bounds__(256) void k_xk(const float* __restrict__ X,
                                            const float* __restrict__ K,
                                            const float* __restrict__ Kb,
                                            ushort_t* __restrict__ XKbf) {
  int k = threadIdx.x & 31;
  int rl = threadIdx.x >> 5;                 // 0..7
  int row = blockIdx.x * 8 + rl;             // global row in [0, B*N)
  const float* xr = X + (size_t)row * Ff;
  float acc = Kb[k];
#pragma unroll 8
  for (int f = 0; f < Ff; ++f) acc += xr[f] * K[f * KD + k];
  XKbf[(size_t)row * KD + k] = f2bf(acc);
}

// ---------------- k_degM: M = bf16(A * sigmoid(XK XK^T)); deg += rowsum(M) ----------
// Tile 64 i-rows x 256 j-cols per block; 4 waves, wave w owns j-cols [64w,64w+64).
__global__ __launch_bounds__(256) void k_degM(const float* __restrict__ A,
                                              const ushort_t* __restrict__ XKbf,
                                              ushort_t* __restrict__ M,
                                              float* __restrict__ deg) {
  int jt = blockIdx.x & 7;
  int it = (blockIdx.x >> 3) & 31;
  int b  = blockIdx.x >> 8;
  int i0 = it * 64, j0 = jt * 256;
  int tid = threadIdx.x;
  int lane = tid & 63, w = tid >> 6;
  int l15 = lane & 15, lh = lane >> 4;

  const ushort_t* XKb = XKbf + (size_t)b * Nn * KD;
  bf16x8 af[4], bfr[4];
#pragma unroll
  for (int m = 0; m < 4; ++m)
    af[m] = *(const bf16x8*)(XKb + (size_t)(i0 + 16 * m + l15) * KD + lh * 8);
#pragma unroll
  for (int n = 0; n < 4; ++n)
    bfr[n] = *(const bf16x8*)(XKb + (size_t)(j0 + 64 * w + 16 * n + l15) * KD + lh * 8);

  f32x4 S[4][4];
#pragma unroll
  for (int m = 0; m < 4; ++m)
#pragma unroll
    for (int n = 0; n < 4; ++n) {
      f32x4 z = {0.f, 0.f, 0.f, 0.f};
      S[m][n] = __builtin_amdgcn_mfma_f32_16x16x32_bf16(af[m], bfr[n], z, 0, 0, 0);
    }

  const float* Ab = A + (size_t)b * Nn * Nn;
  ushort_t* Mb = M + (size_t)b * Nn * Nn;
#pragma unroll
  for (int m = 0; m < 4; ++m) {
#pragma unroll
    for (int r = 0; r < 4; ++r) {
      int row = i0 + 16 * m + lh * 4 + r;
      float ds = 0.f;
#pragma unroll
      for (int n = 0; n < 4; ++n) {
        int col = j0 + 64 * w + 16 * n + l15;
        float d = S[m][n][r];
        float sg = 1.f / (1.f + __expf(-d));
        float mv = Ab[(size_t)row * Nn + col] * sg;
        Mb[(size_t)row * Nn + col] = f2bf(mv);
        ds += mv;
      }
      ds += __shfl_xor(ds, 1, 64);
      ds += __shfl_xor(ds, 2, 64);
      ds += __shfl_xor(ds, 4, 64);
      ds += __shfl_xor(ds, 8, 64);
      if (l15 == 0) atomicAdd(&deg[(size_t)b * Nn + row], ds);
    }
  }
}

// ---------------- k_xw: XWs (fp32, row-major, *isq) and XWsT (bf16, [b][o][j]) ------
__global__ __launch_bounds__(256) void k_xw(const float* __restrict__ X,
                                            const float* __restrict__ W,
                                            const float* __restrict__ Wb,
                                            const float* __restrict__ deg,
                                            float* __restrict__ XWs,
                                            ushort_t* __restrict__ XWsT) {
  __shared__ float Xs[8][Ff];
  int row0 = blockIdx.x * 8;
  int tid = threadIdx.x;
#pragma unroll
  for (int p = 0; p < 2; ++p) {
    int idx = tid + p * 256;
    int r = idx >> 6, c = (idx & 63) * 4;
    *(float4*)&Xs[r][c] = *(const float4*)(X + (size_t)(row0 + r) * Ff + c);
  }
  __syncthreads();
  int o = tid;
  float bias = Wb[o];
  float acc[8];
#pragma unroll
  for (int r = 0; r < 8; ++r) acc[r] = bias;
  for (int f = 0; f < Ff; ++f) {
    float w = W[f * OUTD + o];
#pragma unroll
    for (int r = 0; r < 8; ++r) acc[r] += Xs[r][f] * w;
  }
  int b = row0 / Nn;
  int rl0 = row0 - b * Nn;
  ushort_t mt[8];
#pragma unroll
  for (int r = 0; r < 8; ++r) {
    float is = rsqrtf(1.f + deg[row0 + r]);
    float v = acc[r] * is;
    XWs[(size_t)(row0 + r) * OUTD + o] = v;
    mt[r] = f2bf(v);
  }
  uint4 pk;
  pk.x = (unsigned)mt[0] | ((unsigned)mt[1] << 16);
  pk.y = (unsigned)mt[2] | ((unsigned)mt[3] << 16);
  pk.z = (unsigned)mt[4] | ((unsigned)mt[5] << 16);
  pk.w = (unsigned)mt[6] | ((unsigned)mt[7] << 16);
  *(uint4*)&XWsT[((size_t)b * OUTD + o) * Nn + rl0] = pk;
}

// ---------------- k_main2: out = relu(isq_i * (M @ XWn + XWn_i)) via MFMA ----------
// Tile 32 i-rows x 256 o-cols, 4 waves, wave w owns cols [64w,64w+64). No LDS.
__device__ __forceinline__ void load6(const ushort_t* a0p, const ushort_t* a1p,
                                      const ushort_t* b0p, const ushort_t* b1p,
                                      const ushort_t* b2p, const ushort_t* b3p,
                                      int off,
                                      bf16x8& a0, bf16x8& a1,
                                      bf16x8& b0, bf16x8& b1, bf16x8& b2, bf16x8& b3) {
  a0 = *(const bf16x8*)(a0p + off);
  a1 = *(const bf16x8*)(a1p + off);
  b0 = *(const bf16x8*)(b0p + off);
  b1 = *(const bf16x8*)(b1p + off);
  b2 = *(const bf16x8*)(b2p + off);
  b3 = *(const bf16x8*)(b3p + off);
}

__device__ __forceinline__ void mm8(const bf16x8& a0, const bf16x8& a1,
                                    const bf16x8& b0, const bf16x8& b1,
                                    const bf16x8& b2, const bf16x8& b3,
                                    f32x4 acc[2][4]) {
  acc[0][0] = __builtin_amdgcn_mfma_f32_16x16x32_bf16(a0, b0, acc[0][0], 0, 0, 0);
  acc[0][1] = __builtin_amdgcn_mfma_f32_16x16x32_bf16(a0, b1, acc[0][1], 0, 0, 0);
  acc[0][2] = __builtin_amdgcn_mfma_f32_16x16x32_bf16(a0, b2, acc[0][2], 0, 0, 0);
  acc[0][3] = __builtin_amdgcn_mfma_f32_16x16x32_bf16(a0, b3, acc[0][3], 0, 0, 0);
  acc[1][0] = __builtin_amdgcn_mfma_f32_16x16x32_bf16(a1, b0, acc[1][0], 0, 0, 0);
  acc[1][1] = __builtin_amdgcn_mfma_f32_16x16x32_bf16(a1, b1, acc[1][1], 0, 0, 0);
  acc[1][2] = __builtin_amdgcn_mfma_f32_16x16x32_bf16(a1, b2, acc[1][2], 0, 0, 0);
  acc[1][3] = __builtin_amdgcn_mfma_f32_16x16x32_bf16(a1, b3, acc[1][3], 0, 0, 0);
}

__global__ __launch_bounds__(256) void k_main2(const ushort_t* __restrict__ M,
                                               const ushort_t* __restrict__ XWsT,
                                               const float* __restrict__ XWs,
                                               const float* __restrict__ deg,
                                               float* __restrict__ outX) {
  int it = blockIdx.x & 63;
  int b = blockIdx.x >> 6;
  int i0 = it * 32;
  int tid = threadIdx.x, lane = tid & 63, w = tid >> 6;
  int l15 = lane & 15, lh = lane >> 4;
  const ushort_t* Mb = M + (size_t)b * Nn * Nn;
  const ushort_t* Tb = XWsT + (size_t)b * OUTD * Nn;

  const ushort_t* a0p = Mb + (size_t)(i0 + l15) * Nn + lh * 8;
  const ushort_t* a1p = Mb + (size_t)(i0 + 16 + l15) * Nn + lh * 8;
  const ushort_t* b0p = Tb + (size_t)(64 * w + l15) * Nn + lh * 8;
  const ushort_t* b1p = Tb + (size_t)(64 * w + 16 + l15) * Nn + lh * 8;
  const ushort_t* b2p = Tb + (size_t)(64 * w + 32 + l15) * Nn + lh * 8;
  const ushort_t* b3p = Tb + (size_t)(64 * w + 48 + l15) * Nn + lh * 8;

  f32x4 acc[2][4];
#pragma unroll
  for (int m = 0; m < 2; ++m)
#pragma unroll
    for (int n = 0; n < 4; ++n) acc[m][n] = (f32x4){0.f, 0.f, 0.f, 0.f};

  bf16x8 aA0, aA1, bA0, bA1, bA2, bA3;
  bf16x8 aB0, aB1, bB0, bB1, bB2, bB3;
  bf16x8 aC0, aC1, bC0, bC1, bC2, bC3;
  bf16x8 aD0, aD1, bD0, bD1, bD2, bD3;

  load6(a0p, a1p, b0p, b1p, b2p, b3p, 0 * 32, aA0, aA1, bA0, bA1, bA2, bA3);
  load6(a0p, a1p, b0p, b1p, b2p, b3p, 1 * 32, aB0, aB1, bB0, bB1, bB2, bB3);
  load6(a0p, a1p, b0p, b1p, b2p, b3p, 2 * 32, aC0, aC1, bC0, bC1, bC2, bC3);
  load6(a0p, a1p, b0p, b1p, b2p, b3p, 3 * 32, aD0, aD1, bD0, bD1, bD2, bD3);

  for (int t = 0; t < 64; t += 4) {
    mm8(aA0, aA1, bA0, bA1, bA2, bA3, acc);
    if (t + 4 < 64) load6(a0p, a1p, b0p, b1p, b2p, b3p, (t + 4) * 32, aA0, aA1, bA0, bA1, bA2, bA3);
    mm8(aB0, aB1, bB0, bB1, bB2, bB3, acc);
    if (t + 5 < 64) load6(a0p, a1p, b0p, b1p, b2p, b3p, (t + 5) * 32, aB0, aB1, bB0, bB1, bB2, bB3);
    mm8(aC0, aC1, bC0, bC1, bC2, bC3, acc);
    if (t + 6 < 64) load6(a0p, a1p, b0p, b1p, b2p, b3p, (t + 6) * 32, aC0, aC1, bC0, bC1, bC2, bC3);
    mm8(aD0, aD1, bD0, bD1, bD2, bD3, acc);
    if (t + 7 < 64) load6(a0p, a1p, b0p, b1p, b2p, b3p, (t + 7) * 32, aD0, aD1, bD0, bD1, bD2, bD3);
  }

#pragma unroll
  for (int m = 0; m < 2; ++m) {
#pragma unroll
    for (int r = 0; r < 4; ++r) {
      int row = i0 + 16 * m + lh * 4 + r;
      float is = rsqrtf(1.f + deg[(size_t)b * Nn + row]);
#pragma unroll
      for (int n = 0; n < 4; ++n) {
        int col = 64 * w + 16 * n + l15;
        float v = acc[m][n][r] + XWs[((size_t)b * Nn + row) * OUTD + col];
        outX[((size_t)b * Nn + row) * OUTD + col] = fmaxf(0.f, is * v);
      }
    }
  }
}

// ---------------- n passthrough as float ----------------
__global__ void k_n(const int* __restrict__ n, float* __restrict__ o) {
  if (threadIdx.x < Bz) o[threadIdx.x] = (float)n[threadIdx.x];
}

extern "C" void kernel_launch(void* const* d_in, const int* in_sizes, int n_in,
                              void* d_out, int out_size, void* d_ws, size_t ws_size,
                              hipStream_t stream) {
  const float* X  = (const float*)d_in[0];
  const float* A  = (const float*)d_in[1];
  const int*   nI = (const int*)d_in[2];
  const float* W  = (const float*)d_in[3];
  const float* Wb = (const float*)d_in[4];
  const float* K  = (const float*)d_in[5];
  const float* Kb = (const float*)d_in[6];

  float* outX = (float*)d_out;                              // [8,2048,256] f32
  float* outA = outX + (size_t)Bz * Nn * OUTD;              // [8,2048,2048] f32
  float* outN = outA + (size_t)Bz * Nn * Nn;                // [8]

  // workspace: XKbf (1 MB) | deg (64 KB) | XWs fp32 (16.8 MB) | XWsT bf16 (8.4 MB)
  ushort_t* XKbf = (ushort_t*)d_ws;
  float* deg = (float*)(XKbf + (size_t)Bz * Nn * KD);
  float* XWs = deg + (size_t)Bz * Nn;
  ushort_t* XWsT = (ushort_t*)(XWs + (size_t)Bz * Nn * OUTD);

  // M (bf16, 67 MB) lives in the outA region; A is copied over it afterwards.
  ushort_t* Mws = (ushort_t*)outA;

  hipMemsetAsync(deg, 0, (size_t)Bz * Nn * sizeof(float), stream);
  k_xk  <<<dim3(Bz * Nn / 8),  dim3(256), 0, stream>>>(X, K, Kb, XKbf);
  k_degM<<<dim3(Bz * 32 * 8),  dim3(256), 0, stream>>>(A, XKbf, Mws, deg);
  k_xw  <<<dim3(Bz * Nn / 8),  dim3(256), 0, stream>>>(X, W, Wb, deg, XWs, XWsT);
  k_main2<<<dim3(Bz * 64),     dim3(256), 0, stream>>>(Mws, XWsT, XWs, deg, outX);

  hipMemcpyAsync(outA, A, (size_t)Bz * Nn * Nn * sizeof(float),
                 hipMemcpyDeviceToDevice, stream);
  k_n<<<1, 64, 0, stream>>>(nI, outN);
}

// Round 5
// 467.647 us; speedup vs baseline: 2.8741x; 1.0364x over previous
//
#include <hip/hip_runtime.h>
#include <cstdint>
#include <cstddef>

#define Bz 8
#define Nn 2048
#define Ff 256
#define OUTD 256
#define KD 32

typedef __attribute__((ext_vector_type(8))) short bf16x8;
typedef __attribute__((ext_vector_type(4))) float f32x4;
typedef unsigned short ushort_t;

__device__ __forceinline__ ushort_t f2bf(float f) {
  union { float f; unsigned int u; } v; v.f = f;
  unsigned int r = v.u + 0x7FFFu + ((v.u >> 16) & 1u);   // round-to-nearest-even
  return (ushort_t)(r >> 16);
}

// ---------------- k_xk: XKbf[b,n,k] = bf16( X@K + Kb ) ----------------
__global__ __launch_bounds__(256) void k_xk(const float* __restrict__ X,
                                            const float* __restrict__ K,
                                            const float* __restrict__ Kb,
                                            ushort_t* __restrict__ XKbf) {
  int k = threadIdx.x & 31;
  int rl = threadIdx.x >> 5;
  int row = blockIdx.x * 8 + rl;
  const float* xr = X + (size_t)row * Ff;
  float acc = Kb[k];
#pragma unroll 8
  for (int f = 0; f < Ff; ++f) acc += xr[f] * K[f * KD + k];
  XKbf[(size_t)row * KD + k] = f2bf(acc);
}

// ---- k_degM: M = bf16(A*sigmoid(XK XK^T)); deg += rowsum(M); optional A->Ao copy ----
__global__ __launch_bounds__(256) void k_degM(const float* __restrict__ A,
                                              const ushort_t* __restrict__ XKbf,
                                              ushort_t* __restrict__ M,
                                              float* __restrict__ deg,
                                              float* __restrict__ Ao) {
  int jt = blockIdx.x & 7;
  int it = (blockIdx.x >> 3) & 31;
  int b  = blockIdx.x >> 8;
  int i0 = it * 64, j0 = jt * 256;
  int tid = threadIdx.x;
  int lane = tid & 63, w = tid >> 6;
  int l15 = lane & 15, lh = lane >> 4;

  const ushort_t* XKb = XKbf + (size_t)b * Nn * KD;
  bf16x8 af[4], bfr[4];
#pragma unroll
  for (int m = 0; m < 4; ++m)
    af[m] = *(const bf16x8*)(XKb + (size_t)(i0 + 16 * m + l15) * KD + lh * 8);
#pragma unroll
  for (int n = 0; n < 4; ++n)
    bfr[n] = *(const bf16x8*)(XKb + (size_t)(j0 + 64 * w + 16 * n + l15) * KD + lh * 8);

  f32x4 S[4][4];
#pragma unroll
  for (int m = 0; m < 4; ++m)
#pragma unroll
    for (int n = 0; n < 4; ++n) {
      f32x4 z = {0.f, 0.f, 0.f, 0.f};
      S[m][n] = __builtin_amdgcn_mfma_f32_16x16x32_bf16(af[m], bfr[n], z, 0, 0, 0);
    }

  const float* Ab = A + (size_t)b * Nn * Nn;
  ushort_t* Mb = M + (size_t)b * Nn * Nn;
  float* Aob = Ao ? Ao + (size_t)b * Nn * Nn : nullptr;
#pragma unroll
  for (int m = 0; m < 4; ++m) {
#pragma unroll
    for (int r = 0; r < 4; ++r) {
      int row = i0 + 16 * m + lh * 4 + r;
      float ds = 0.f;
#pragma unroll
      for (int n = 0; n < 4; ++n) {
        int col = j0 + 64 * w + 16 * n + l15;
        float a = Ab[(size_t)row * Nn + col];
        if (Aob) Aob[(size_t)row * Nn + col] = a;          // fused A passthrough
        float d = S[m][n][r];
        float sg = 1.f / (1.f + __expf(-d));
        float mv = a * sg;
        Mb[(size_t)row * Nn + col] = f2bf(mv);
        ds += mv;
      }
      ds += __shfl_xor(ds, 1, 64);
      ds += __shfl_xor(ds, 2, 64);
      ds += __shfl_xor(ds, 4, 64);
      ds += __shfl_xor(ds, 8, 64);
      if (l15 == 0) atomicAdd(&deg[(size_t)b * Nn + row], ds);
    }
  }
}

// ---------------- k_xw: XWs (fp32 row-major, *isq) and XWsT (bf16, [b][o][j]) -------
__global__ __launch_bounds__(256) void k_xw(const float* __restrict__ X,
                                            const float* __restrict__ W,
                                            const float* __restrict__ Wb,
                                            const float* __restrict__ deg,
                                            float* __restrict__ XWs,
                                            ushort_t* __restrict__ XWsT) {
  __shared__ float Xs[8][Ff];
  int row0 = blockIdx.x * 8;
  int tid = threadIdx.x;
#pragma unroll
  for (int p = 0; p < 2; ++p) {
    int idx = tid + p * 256;
    int r = idx >> 6, c = (idx & 63) * 4;
    *(float4*)&Xs[r][c] = *(const float4*)(X + (size_t)(row0 + r) * Ff + c);
  }
  __syncthreads();
  int o = tid;
  float bias = Wb[o];
  float acc[8];
#pragma unroll
  for (int r = 0; r < 8; ++r) acc[r] = bias;
  for (int f = 0; f < Ff; ++f) {
    float w = W[f * OUTD + o];
#pragma unroll
    for (int r = 0; r < 8; ++r) acc[r] += Xs[r][f] * w;
  }
  int b = row0 / Nn;
  int rl0 = row0 - b * Nn;
  ushort_t mt[8];
#pragma unroll
  for (int r = 0; r < 8; ++r) {
    float is = rsqrtf(1.f + deg[row0 + r]);
    float v = acc[r] * is;
    XWs[(size_t)(row0 + r) * OUTD + o] = v;
    mt[r] = f2bf(v);
  }
  uint4 pk;
  pk.x = (unsigned)mt[0] | ((unsigned)mt[1] << 16);
  pk.y = (unsigned)mt[2] | ((unsigned)mt[3] << 16);
  pk.z = (unsigned)mt[4] | ((unsigned)mt[5] << 16);
  pk.w = (unsigned)mt[6] | ((unsigned)mt[7] << 16);
  *(uint4*)&XWsT[((size_t)b * OUTD + o) * Nn + rl0] = pk;
}

// ---------------- k_main3: out = relu(isq_i*(M@XWn + XWn_i)), LDS double-buffered ----
// Tile 32 i x 256 o, full K. batch = blockIdx&7 (XCD-affine: B panel stays in XCD L2).
// Reg-staged global->LDS (compiler cannot sink loads past ds_write+barrier),
// XOR-swizzled LDS rows (64B rows, byte ^= (row&7)<<4) for conflict-free ds_read_b128.
#define SWZB(row, grp16) ((unsigned)((row) * 64 + (((grp16) * 16) ^ (((row) & 7) << 4))))

__global__ __launch_bounds__(256) void k_main3(const ushort_t* __restrict__ M,
                                               const ushort_t* __restrict__ XWsT,
                                               const float* __restrict__ XWs,
                                               const float* __restrict__ deg,
                                               float* __restrict__ outX) {
  __shared__ __align__(16) ushort_t As[2][32 * 32];
  __shared__ __align__(16) ushort_t Bs[2][256 * 32];
  int b  = blockIdx.x & 7;
  int i0 = (blockIdx.x >> 3) * 32;
  int tid = threadIdx.x, lane = tid & 63, w = tid >> 6;
  int l15 = lane & 15, lh = lane >> 4;
  const ushort_t* Mb = M + (size_t)b * Nn * Nn;
  const ushort_t* Tb = XWsT + (size_t)b * OUTD * Nn;

  int r4 = tid >> 2;            // B: rows p*64+r4 ; A: row r4 (tid<128)
  int g3 = tid & 3;             // 16B group within 64B row
  const ushort_t* tb0 = Tb + (size_t)r4 * Nn + g3 * 8;
  const ushort_t* mb0 = Mb + (size_t)(i0 + (r4 & 31)) * Nn + g3 * 8;

  bf16x8 rB[4], rA;
  f32x4 acc[2][4];
#pragma unroll
  for (int m = 0; m < 2; ++m)
#pragma unroll
    for (int n = 0; n < 4; ++n) acc[m][n] = (f32x4){0.f, 0.f, 0.f, 0.f};

#define LOAD_REGS(k0)                                                          \
  {                                                                            \
    _Pragma("unroll")                                                          \
    for (int p = 0; p < 4; ++p)                                                \
      rB[p] = *(const bf16x8*)(tb0 + (size_t)p * 64 * Nn + (k0));              \
    if (tid < 128) rA = *(const bf16x8*)(mb0 + (k0));                          \
  }

#define WRITE_LDS(buf)                                                         \
  {                                                                            \
    _Pragma("unroll")                                                          \
    for (int p = 0; p < 4; ++p)                                                \
      *(bf16x8*)((char*)&Bs[buf][0] + SWZB(p * 64 + r4, g3)) = rB[p];          \
    if (tid < 128) *(bf16x8*)((char*)&As[buf][0] + SWZB(r4, g3)) = rA;         \
  }

  LOAD_REGS(0);
  WRITE_LDS(0);
  __syncthreads();
  LOAD_REGS(32);

  int cur = 0;
  for (int t = 0; t < 64; ++t) {
    bf16x8 af0 = *(const bf16x8*)((char*)&As[cur][0] + SWZB(l15, lh));
    bf16x8 af1 = *(const bf16x8*)((char*)&As[cur][0] + SWZB(16 + l15, lh));
    bf16x8 bf0 = *(const bf16x8*)((char*)&Bs[cur][0] + SWZB(64 * w + l15, lh));
    bf16x8 bf1 = *(const bf16x8*)((char*)&Bs[cur][0] + SWZB(64 * w + 16 + l15, lh));
    bf16x8 bf2 = *(const bf16x8*)((char*)&Bs[cur][0] + SWZB(64 * w + 32 + l15, lh));
    bf16x8 bf3 = *(const bf16x8*)((char*)&Bs[cur][0] + SWZB(64 * w + 48 + l15, lh));
    acc[0][0] = __builtin_amdgcn_mfma_f32_16x16x32_bf16(af0, bf0, acc[0][0], 0, 0, 0);
    acc[0][1] = __builtin_amdgcn_mfma_f32_16x16x32_bf16(af0, bf1, acc[0][1], 0, 0, 0);
    acc[0][2] = __builtin_amdgcn_mfma_f32_16x16x32_bf16(af0, bf2, acc[0][2], 0, 0, 0);
    acc[0][3] = __builtin_amdgcn_mfma_f32_16x16x32_bf16(af0, bf3, acc[0][3], 0, 0, 0);
    acc[1][0] = __builtin_amdgcn_mfma_f32_16x16x32_bf16(af1, bf0, acc[1][0], 0, 0, 0);
    acc[1][1] = __builtin_amdgcn_mfma_f32_16x16x32_bf16(af1, bf1, acc[1][1], 0, 0, 0);
    acc[1][2] = __builtin_amdgcn_mfma_f32_16x16x32_bf16(af1, bf2, acc[1][2], 0, 0, 0);
    acc[1][3] = __builtin_amdgcn_mfma_f32_16x16x32_bf16(af1, bf3, acc[1][3], 0, 0, 0);
    if (t < 63) WRITE_LDS(cur ^ 1);          // waits vmcnt for regs(t+1) here
    if (t < 62) LOAD_REGS((t + 2) * 32);     // issue next, lands during next MFMAs
    __syncthreads();
    cur ^= 1;
  }

#pragma unroll
  for (int m = 0; m < 2; ++m) {
#pragma unroll
    for (int r = 0; r < 4; ++r) {
      int row = i0 + 16 * m + lh * 4 + r;
      float is = rsqrtf(1.f + deg[(size_t)b * Nn + row]);
#pragma unroll
      for (int n = 0; n < 4; ++n) {
        int col = 64 * w + 16 * n + l15;
        float v = acc[m][n][r] + XWs[((size_t)b * Nn + row) * OUTD + col];
        outX[((size_t)b * Nn + row) * OUTD + col] = fmaxf(0.f, is * v);
      }
    }
  }
}

// ---------------- n passthrough as float ----------------
__global__ void k_n(const int* __restrict__ n, float* __restrict__ o) {
  if (threadIdx.x < Bz) o[threadIdx.x] = (float)n[threadIdx.x];
}

extern "C" void kernel_launch(void* const* d_in, const int* in_sizes, int n_in,
                              void* d_out, int out_size, void* d_ws, size_t ws_size,
                              hipStream_t stream) {
  const float* X  = (const float*)d_in[0];
  const float* A  = (const float*)d_in[1];
  const int*   nI = (const int*)d_in[2];
  const float* W  = (const float*)d_in[3];
  const float* Wb = (const float*)d_in[4];
  const float* K  = (const float*)d_in[5];
  const float* Kb = (const float*)d_in[6];

  float* outX = (float*)d_out;                              // [8,2048,256] f32
  float* outA = outX + (size_t)Bz * Nn * OUTD;              // [8,2048,2048] f32
  float* outN = outA + (size_t)Bz * Nn * Nn;                // [8]

  // ws layout: XKbf 1MB | deg 64KB | XWs 16.8MB | XWsT 8.4MB | (M 67MB if it fits)
  ushort_t* XKbf = (ushort_t*)d_ws;
  float* deg = (float*)(XKbf + (size_t)Bz * Nn * KD);
  float* XWs = deg + (size_t)Bz * Nn;
  ushort_t* XWsT = (ushort_t*)(XWs + (size_t)Bz * Nn * OUTD);
  ushort_t* Mws_ws = XWsT + (size_t)Bz * OUTD * Nn;

  const size_t need = (size_t)Bz * Nn * KD * 2 + (size_t)Bz * Nn * 4 +
                      (size_t)Bz * Nn * OUTD * 4 + (size_t)Bz * OUTD * Nn * 2 +
                      (size_t)Bz * Nn * Nn * 2;
  bool fused = ws_size >= need;             // constant per process: capture-safe
  ushort_t* Mp = fused ? Mws_ws : (ushort_t*)outA;
  float* AoP  = fused ? outA : nullptr;

  hipMemsetAsync(deg, 0, (size_t)Bz * Nn * sizeof(float), stream);
  k_xk  <<<dim3(Bz * Nn / 8), dim3(256), 0, stream>>>(X, K, Kb, XKbf);
  k_degM<<<dim3(Bz * 32 * 8), dim3(256), 0, stream>>>(A, XKbf, Mp, deg, AoP);
  k_xw  <<<dim3(Bz * Nn / 8), dim3(256), 0, stream>>>(X, W, Wb, deg, XWs, XWsT);
  k_main3<<<dim3(Bz * 64),    dim3(256), 0, stream>>>(Mp, XWsT, XWs, deg, outX);
  if (!fused) {
    hipMemcpyAsync(outA, A, (size_t)Bz * Nn * Nn * sizeof(float),
                   hipMemcpyDeviceToDevice, stream);
  }
  k_n<<<1, 64, 0, stream>>>(nI, outN);
}